// Round 17
// baseline (129.807 us; speedup 1.0000x reference)
//
#include <hip/hip_runtime.h>
#include <hip/hip_bf16.h>

#define C_DIM 256
#define B_SZ 32
#define NS 4096
#define NT_Z 256
#define TOPK_K 32
#define NWIN 64
#define WTOK 64

typedef __attribute__((ext_vector_type(8))) short short8;
typedef __attribute__((ext_vector_type(4))) float f32x4;

static __device__ inline unsigned short f2b(float f) {
  union { float f; unsigned int u; } x; x.f = f;
  unsigned int u = x.u;
  return (unsigned short)((u + 0x7FFFu + ((u >> 16) & 1u)) >> 16);
}
static __device__ inline float b2f(unsigned int h16) {   // low 16 bits = bf16
  union { unsigned int u; float f; } x; x.u = h16 << 16;
  return x.f;
}

// ---------------- kernel 1: weights f32->bf16 (vectorized) + z_max partials -
__global__ void prep_kernel(const float* __restrict__ Wd, const float* __restrict__ Wu,
                            unsigned short* __restrict__ Wdb, unsigned short* __restrict__ Wub,
                            const float* __restrict__ z, float* __restrict__ zpart) {
  int blk = blockIdx.x;
  if (blk < 64) {
    int i = blk * 256 + threadIdx.x;     // float4 id, 16384 per matrix
    float4 a = ((const float4*)Wd)[i];
    float4 c = ((const float4*)Wu)[i];
    ushort4 ha, hc;
    ha.x = f2b(a.x); ha.y = f2b(a.y); ha.z = f2b(a.z); ha.w = f2b(a.w);
    hc.x = f2b(c.x); hc.y = f2b(c.y); hc.z = f2b(c.z); hc.w = f2b(c.w);
    ((ushort4*)Wdb)[i] = ha;
    ((ushort4*)Wub)[i] = hc;
  } else {
    int i = blk - 64;                    // 0..255
    int b = i >> 3, ch = i & 7;
    int c = threadIdx.x;
    const float* p = z + ((size_t)b * NT_Z + ch * 32) * C_DIM + c;
    float m = p[0];
    for (int n = 1; n < 32; ++n) m = fmaxf(m, p[(size_t)n * C_DIM]);
    zpart[(size_t)i * C_DIM + c] = m;
  }
}

// ---------------- kernel 2: window scores (+ zmax final reduce) -------------
__global__ __launch_bounds__(256) void winscore_kernel(const float* __restrict__ x,
                                                       const float* __restrict__ zpart,
                                                       float* __restrict__ score) {
  int b = blockIdx.x >> 6;
  int w = blockIdx.x & 63;
  int wy = w >> 3, wx = w & 7;

  __shared__ float zs[C_DIM];
  {
    float m = zpart[(size_t)(b * 8) * C_DIM + threadIdx.x];
    #pragma unroll
    for (int ch = 1; ch < 8; ++ch)
      m = fmaxf(m, zpart[(size_t)(b * 8 + ch) * C_DIM + threadIdx.x]);
    zs[threadIdx.x] = m;
  }
  __syncthreads();

  int wv = threadIdx.x >> 6;
  int ln = threadIdx.x & 63;

  float a0 = 0.f, a1 = 0.f, a2 = 0.f, a3 = 0.f;
  for (int t = 0; t < 16; ++t) {
    int tok = wv * 16 + t;
    int iy = tok >> 3, ix = tok & 7;
    int n = (wy * 8 + iy) * 64 + wx * 8 + ix;
    const float4 v = *(const float4*)(x + ((size_t)b * NS + n) * C_DIM + ln * 4);
    a0 += v.x; a1 += v.y; a2 += v.z; a3 += v.w;
  }
  const float4 z4 = ((const float4*)zs)[ln];
  float p = a0 * z4.x + a1 * z4.y + a2 * z4.z + a3 * z4.w;
  for (int off = 32; off >= 1; off >>= 1) p += __shfl_xor(p, off);

  __shared__ float wsum[4];
  if (ln == 0) wsum[wv] = p;
  __syncthreads();
  if (threadIdx.x == 0) score[blockIdx.x] = wsum[0] + wsum[1] + wsum[2] + wsum[3];
}

// ---------------- kernel 3: paired-window fused kernel ----------------------
// R10 structure, but each block processes TWO consecutive ranks of one batch:
// grid 512 (= 2 blocks/CU, one even round).  The topk phase runs once for
// both; window 1's 16 x-loads are issued right after window 0's GEMM2 (only
// epilogue code is live there -> no register-pressure conflict), so window 1
// skips its staging stall.  Weights reload per window (L2-warm).
// XOR swizzle: byte_in_row ^= (row & 7) << 4.
__global__ __launch_bounds__(256, 2) void fused_win(
    const float* __restrict__ x, const float* __restrict__ score,
    const unsigned short* __restrict__ Wdb, const unsigned short* __restrict__ Wub,
    const float* __restrict__ bd, const float* __restrict__ bu,
    float* __restrict__ out)
{
  __shared__ unsigned short xe_s[WTOK * C_DIM];  // 32 KB
  __shared__ unsigned short t_s[WTOK * C_DIM];   // 32 KB (t, then up)
  __shared__ float sc[NWIN];
  __shared__ int wsel2_s[2];

  const int bk = blockIdx.x;       // 0..511
  const int b = bk >> 4;
  const int kk0 = (bk & 15) * 2;
  const int tid = threadIdx.x;

  // ---- top-k rank select for BOTH ranks this block owns ----
  if (tid < NWIN) sc[tid] = score[b * NWIN + tid];
  __syncthreads();
  if (tid < NWIN) {
    float v = sc[tid];
    int rank = 0;
    #pragma unroll
    for (int j = 0; j < NWIN; ++j) {
      float sj = sc[j];
      rank += (sj > v) || (sj == v && j < tid);
    }
    int rr = rank - kk0;
    if (rr >= 0 && rr < 2) wsel2_s[rr] = tid;
  }
  __syncthreads();

  const int wv = tid >> 6;
  const int ln = tid & 63;
  const int lr = ln & 15;   // A-row / B-col / D-col
  const int lg = ln >> 4;   // k-subgroup
  const int c4 = tid & 63;  // float4 column for staging/output
  const int m0w = tid >> 6; // starting row (0..3)

  const unsigned short* wdbase = Wdb + ((size_t)(wv * 64 + lr)) * C_DIM + lg * 8;
  const unsigned short* wubase = Wub + ((size_t)(wv * 64 + lr)) * C_DIM + lg * 8;
  const float* xb = x + (size_t)b * NS * C_DIM + c4 * 4;

  // =================== WINDOW 0 ===================
  const int wsel0 = wsel2_s[0];
  const int wy0 = wsel0 >> 3, wx0 = wsel0 & 7;
  const int wsel1 = wsel2_s[1];
  const int wy1 = wsel1 >> 3, wx1 = wsel1 & 7;

  // ---- issue GEMM1 weights (land during staging) ----
  short8 wreg[8][4];
  #pragma unroll
  for (int ks = 0; ks < 8; ++ks)
    #pragma unroll
    for (int nt = 0; nt < 4; ++nt)
      wreg[ks][nt] = *(const short8*)(wdbase + nt * 16 * C_DIM + ks * 32);

  // ---- stage xe(w0): all 16 loads in flight, then convert+write ----
  {
    float4 xv[16];
    #pragma unroll
    for (int i = 0; i < 16; ++i) {
      int m = m0w + i * 4;
      int n = (wy0 * 8 + (m >> 3)) * 64 + wx0 * 8 + (m & 7);
      xv[i] = *(const float4*)(xb + (size_t)n * C_DIM);
    }
    #pragma unroll
    for (int i = 0; i < 16; ++i) {
      int m = m0w + i * 4;
      ushort4 h;
      h.x = f2b(xv[i].x); h.y = f2b(xv[i].y); h.z = f2b(xv[i].z); h.w = f2b(xv[i].w);
      int byteoff = m * 512 + ((c4 * 8) ^ ((m & 7) << 4));
      *(ushort4*)((char*)xe_s + byteoff) = h;
    }
  }
  __syncthreads();

  // ---- GEMM1(w0) ----
  f32x4 acc[4][4];
  #pragma unroll
  for (int a = 0; a < 4; ++a)
    #pragma unroll
    for (int n2 = 0; n2 < 4; ++n2) acc[a][n2] = (f32x4){0.f, 0.f, 0.f, 0.f};

  #pragma unroll
  for (int ks = 0; ks < 8; ++ks) {
    const int kb = ks * 64 + lg * 16;
    short8 af[4];
    #pragma unroll
    for (int mt = 0; mt < 4; ++mt) {
      int m = mt * 16 + lr;
      af[mt] = *(const short8*)((const char*)xe_s + m * 512 + (kb ^ ((m & 7) << 4)));
    }
    #pragma unroll
    for (int mt = 0; mt < 4; ++mt)
      #pragma unroll
      for (int nt = 0; nt < 4; ++nt)
        acc[mt][nt] = __builtin_amdgcn_mfma_f32_16x16x32_bf16(af[mt], wreg[ks][nt], acc[mt][nt], 0, 0, 0);
  }

  // ---- epi1(w0): t = acc + bd -> bf16 -> t_s ----
  #pragma unroll
  for (int nt = 0; nt < 4; ++nt) {
    int o = wv * 64 + nt * 16 + lr;
    float bdv = bd[o];
    #pragma unroll
    for (int mt = 0; mt < 4; ++mt) {
      #pragma unroll
      for (int r = 0; r < 4; ++r) {
        int m = mt * 16 + lg * 4 + r;
        float v = acc[mt][nt][r] + bdv;
        *(unsigned short*)((char*)t_s + m * 512 + ((o * 2) ^ ((m & 7) << 4))) = f2b(v);
      }
    }
  }

  // ---- issue GEMM2 weights (land under the barrier) ----
  short8 wreg2[8][4];
  #pragma unroll
  for (int ks = 0; ks < 8; ++ks)
    #pragma unroll
    for (int nt = 0; nt < 4; ++nt)
      wreg2[ks][nt] = *(const short8*)(wubase + nt * 16 * C_DIM + ks * 32);

  __syncthreads();

  // ---- GEMM2(w0) ----
  f32x4 acc2[4][4];
  #pragma unroll
  for (int a = 0; a < 4; ++a)
    #pragma unroll
    for (int n2 = 0; n2 < 4; ++n2) acc2[a][n2] = (f32x4){0.f, 0.f, 0.f, 0.f};

  #pragma unroll
  for (int ks = 0; ks < 8; ++ks) {
    const int g = ks >> 1;
    const int dd = ((g & 1) ? -1 : 1) * ((g & 2) ? 8 : 1);
    const int kb = ks * 64 + lg * 16;
    short8 af[4];
    #pragma unroll
    for (int mt = 0; mt < 4; ++mt) {
      int m = mt * 16 + lr;
      int pos = (g & 2) ? (m >> 3) : (m & 7);
      bool ok = (g & 1) ? (pos > 0) : (pos < 7);
      int ms = m + dd;
      ms = ms < 0 ? 0 : (ms > 63 ? 63 : ms);
      short8 v = *(const short8*)((const char*)t_s + ms * 512 + (kb ^ ((ms & 7) << 4)));
      const short8 zed = {0, 0, 0, 0, 0, 0, 0, 0};
      af[mt] = ok ? v : zed;
    }
    #pragma unroll
    for (int mt = 0; mt < 4; ++mt)
      #pragma unroll
      for (int nt = 0; nt < 4; ++nt)
        acc2[mt][nt] = __builtin_amdgcn_mfma_f32_16x16x32_bf16(af[mt], wreg2[ks][nt], acc2[mt][nt], 0, 0, 0);
  }

  // ---- prefetch window 1's x (lands under epilogue; wreg/wreg2 dead) ----
  float4 xv1[16];
  #pragma unroll
  for (int i = 0; i < 16; ++i) {
    int m = m0w + i * 4;
    int n = (wy1 * 8 + (m >> 3)) * 64 + wx1 * 8 + (m & 7);
    xv1[i] = *(const float4*)(xb + (size_t)n * C_DIM);
  }

  __syncthreads();   // all t_s reads done; t_s free for up

  // ---- epi2a(w0): up -> bf16 -> t_s ----
  #pragma unroll
  for (int nt = 0; nt < 4; ++nt) {
    int c = wv * 64 + nt * 16 + lr;
    #pragma unroll
    for (int mt = 0; mt < 4; ++mt) {
      #pragma unroll
      for (int r = 0; r < 4; ++r) {
        int m = mt * 16 + lg * 4 + r;
        *(unsigned short*)((char*)t_s + m * 512 + ((c * 2) ^ ((m & 7) << 4))) = f2b(acc2[mt][nt][r]);
      }
    }
  }
  __syncthreads();

  // ---- epi2b(w0): coalesced row writes ----
  {
    const float4 bu4 = *(const float4*)(bu + c4 * 4);
    float* ob = out + (size_t)(b * 32 + kk0) * WTOK * C_DIM + c4 * 4;
    #pragma unroll
    for (int i = 0; i < 16; ++i) {
      int m = m0w + i * 4;
      int off = m * 512 + ((c4 * 8) ^ ((m & 7) << 4));
      ushort4 xe4 = *(const ushort4*)((const char*)xe_s + off);
      ushort4 up4 = *(const ushort4*)((const char*)t_s + off);
      float4 o;
      o.x = b2f(xe4.x) + b2f(up4.x) + bu4.x;
      o.y = b2f(xe4.y) + b2f(up4.y) + bu4.y;
      o.z = b2f(xe4.z) + b2f(up4.z) + bu4.z;
      o.w = b2f(xe4.w) + b2f(up4.w) + bu4.w;
      *(float4*)(ob + (size_t)m * C_DIM) = o;
    }
  }
  __syncthreads();   // xe_s reads done; safe to overwrite for window 1

  // =================== WINDOW 1 ===================
  // ---- reload GEMM1 weights (L2-warm; latency under convert+barrier) ----
  #pragma unroll
  for (int ks = 0; ks < 8; ++ks)
    #pragma unroll
    for (int nt = 0; nt < 4; ++nt)
      wreg[ks][nt] = *(const short8*)(wdbase + nt * 16 * C_DIM + ks * 32);

  // ---- stage xe(w1) from prefetched regs (no load stall) ----
  #pragma unroll
  for (int i = 0; i < 16; ++i) {
    int m = m0w + i * 4;
    ushort4 h;
    h.x = f2b(xv1[i].x); h.y = f2b(xv1[i].y); h.z = f2b(xv1[i].z); h.w = f2b(xv1[i].w);
    int byteoff = m * 512 + ((c4 * 8) ^ ((m & 7) << 4));
    *(ushort4*)((char*)xe_s + byteoff) = h;
  }
  __syncthreads();

  // ---- GEMM1(w1) ----
  #pragma unroll
  for (int a = 0; a < 4; ++a)
    #pragma unroll
    for (int n2 = 0; n2 < 4; ++n2) acc[a][n2] = (f32x4){0.f, 0.f, 0.f, 0.f};

  #pragma unroll
  for (int ks = 0; ks < 8; ++ks) {
    const int kb = ks * 64 + lg * 16;
    short8 af[4];
    #pragma unroll
    for (int mt = 0; mt < 4; ++mt) {
      int m = mt * 16 + lr;
      af[mt] = *(const short8*)((const char*)xe_s + m * 512 + (kb ^ ((m & 7) << 4)));
    }
    #pragma unroll
    for (int mt = 0; mt < 4; ++mt)
      #pragma unroll
      for (int nt = 0; nt < 4; ++nt)
        acc[mt][nt] = __builtin_amdgcn_mfma_f32_16x16x32_bf16(af[mt], wreg[ks][nt], acc[mt][nt], 0, 0, 0);
  }

  // ---- epi1(w1) ----
  #pragma unroll
  for (int nt = 0; nt < 4; ++nt) {
    int o = wv * 64 + nt * 16 + lr;
    float bdv = bd[o];
    #pragma unroll
    for (int mt = 0; mt < 4; ++mt) {
      #pragma unroll
      for (int r = 0; r < 4; ++r) {
        int m = mt * 16 + lg * 4 + r;
        float v = acc[mt][nt][r] + bdv;
        *(unsigned short*)((char*)t_s + m * 512 + ((o * 2) ^ ((m & 7) << 4))) = f2b(v);
      }
    }
  }

  // ---- reload GEMM2 weights ----
  #pragma unroll
  for (int ks = 0; ks < 8; ++ks)
    #pragma unroll
    for (int nt = 0; nt < 4; ++nt)
      wreg2[ks][nt] = *(const short8*)(wubase + nt * 16 * C_DIM + ks * 32);

  __syncthreads();

  // ---- GEMM2(w1) ----
  #pragma unroll
  for (int a = 0; a < 4; ++a)
    #pragma unroll
    for (int n2 = 0; n2 < 4; ++n2) acc2[a][n2] = (f32x4){0.f, 0.f, 0.f, 0.f};

  #pragma unroll
  for (int ks = 0; ks < 8; ++ks) {
    const int g = ks >> 1;
    const int dd = ((g & 1) ? -1 : 1) * ((g & 2) ? 8 : 1);
    const int kb = ks * 64 + lg * 16;
    short8 af[4];
    #pragma unroll
    for (int mt = 0; mt < 4; ++mt) {
      int m = mt * 16 + lr;
      int pos = (g & 2) ? (m >> 3) : (m & 7);
      bool ok = (g & 1) ? (pos > 0) : (pos < 7);
      int ms = m + dd;
      ms = ms < 0 ? 0 : (ms > 63 ? 63 : ms);
      short8 v = *(const short8*)((const char*)t_s + ms * 512 + (kb ^ ((ms & 7) << 4)));
      const short8 zed = {0, 0, 0, 0, 0, 0, 0, 0};
      af[mt] = ok ? v : zed;
    }
    #pragma unroll
    for (int mt = 0; mt < 4; ++mt)
      #pragma unroll
      for (int nt = 0; nt < 4; ++nt)
        acc2[mt][nt] = __builtin_amdgcn_mfma_f32_16x16x32_bf16(af[mt], wreg2[ks][nt], acc2[mt][nt], 0, 0, 0);
  }
  __syncthreads();

  // ---- epi2a(w1) ----
  #pragma unroll
  for (int nt = 0; nt < 4; ++nt) {
    int c = wv * 64 + nt * 16 + lr;
    #pragma unroll
    for (int mt = 0; mt < 4; ++mt) {
      #pragma unroll
      for (int r = 0; r < 4; ++r) {
        int m = mt * 16 + lg * 4 + r;
        *(unsigned short*)((char*)t_s + m * 512 + ((c * 2) ^ ((m & 7) << 4))) = f2b(acc2[mt][nt][r]);
      }
    }
  }
  __syncthreads();

  // ---- epi2b(w1): coalesced row writes ----
  {
    const float4 bu4 = *(const float4*)(bu + c4 * 4);
    float* ob = out + (size_t)(b * 32 + kk0 + 1) * WTOK * C_DIM + c4 * 4;
    #pragma unroll
    for (int i = 0; i < 16; ++i) {
      int m = m0w + i * 4;
      int off = m * 512 + ((c4 * 8) ^ ((m & 7) << 4));
      ushort4 xe4 = *(const ushort4*)((const char*)xe_s + off);
      ushort4 up4 = *(const ushort4*)((const char*)t_s + off);
      float4 o;
      o.x = b2f(xe4.x) + b2f(up4.x) + bu4.x;
      o.y = b2f(xe4.y) + b2f(up4.y) + bu4.y;
      o.z = b2f(xe4.z) + b2f(up4.z) + bu4.z;
      o.w = b2f(xe4.w) + b2f(up4.w) + bu4.w;
      *(float4*)(ob + (size_t)m * C_DIM) = o;
    }
  }
}

// ---------------- launch ----------------
extern "C" void kernel_launch(void* const* d_in, const int* in_sizes, int n_in,
                              void* d_out, int out_size, void* d_ws, size_t ws_size,
                              hipStream_t stream) {
  const float* z  = (const float*)d_in[0];
  const float* x  = (const float*)d_in[1];
  const float* Wd = (const float*)d_in[2];
  const float* bd = (const float*)d_in[3];
  const float* Wu = (const float*)d_in[4];
  const float* bu = (const float*)d_in[5];
  float* out = (float*)d_out;

  char* ws = (char*)d_ws;
  unsigned short* Wdb = (unsigned short*)(ws);            // 0      .. 131072
  unsigned short* Wub = (unsigned short*)(ws + 131072);   // 131072 .. 262144
  float* zpart = (float*)(ws + 262144);                   // 262144 .. 524288 (32*8*256 f32)
  float* score = (float*)(ws + 524288);                   // 524288 .. 532480

  hipLaunchKernelGGL(prep_kernel, dim3(320), dim3(256), 0, stream, Wd, Wu, Wdb, Wub, z, zpart);
  hipLaunchKernelGGL(winscore_kernel, dim3(B_SZ * NWIN), dim3(256), 0, stream, x, zpart, score);
  hipLaunchKernelGGL(fused_win, dim3(B_SZ * TOPK_K / 2), dim3(256), 0, stream,
                     x, score, Wdb, Wub, bd, bu, out);
}

// Round 18
// 81.518 us; speedup vs baseline: 1.5924x; 1.5924x over previous
//
#include <hip/hip_runtime.h>
#include <hip/hip_bf16.h>

#define C_DIM 256
#define B_SZ 32
#define NS 4096
#define NT_Z 256
#define TOPK_K 32
#define NWIN 64
#define WTOK 64

typedef __attribute__((ext_vector_type(8))) short short8;
typedef __attribute__((ext_vector_type(4))) float f32x4;

static __device__ inline unsigned short f2b(float f) {
  union { float f; unsigned int u; } x; x.f = f;
  unsigned int u = x.u;
  return (unsigned short)((u + 0x7FFFu + ((u >> 16) & 1u)) >> 16);
}
static __device__ inline float b2f(unsigned int h16) {   // low 16 bits = bf16
  union { unsigned int u; float f; } x; x.u = h16 << 16;
  return x.f;
}

// ---------------- kernel 1: weights f32->bf16 (vectorized) + z_max partials -
__global__ void prep_kernel(const float* __restrict__ Wd, const float* __restrict__ Wu,
                            unsigned short* __restrict__ Wdb, unsigned short* __restrict__ Wub,
                            const float* __restrict__ z, float* __restrict__ zpart) {
  int blk = blockIdx.x;
  if (blk < 64) {
    int i = blk * 256 + threadIdx.x;     // float4 id, 16384 per matrix
    float4 a = ((const float4*)Wd)[i];
    float4 c = ((const float4*)Wu)[i];
    ushort4 ha, hc;
    ha.x = f2b(a.x); ha.y = f2b(a.y); ha.z = f2b(a.z); ha.w = f2b(a.w);
    hc.x = f2b(c.x); hc.y = f2b(c.y); hc.z = f2b(c.z); hc.w = f2b(c.w);
    ((ushort4*)Wdb)[i] = ha;
    ((ushort4*)Wub)[i] = hc;
  } else {
    int i = blk - 64;                    // 0..255
    int b = i >> 3, ch = i & 7;
    int c = threadIdx.x;
    const float* p = z + ((size_t)b * NT_Z + ch * 32) * C_DIM + c;
    float m = p[0];
    for (int n = 1; n < 32; ++n) m = fmaxf(m, p[(size_t)n * C_DIM]);
    zpart[(size_t)i * C_DIM + c] = m;
  }
}

// ---------------- kernel 2: window scores (+ zmax final reduce) -------------
__global__ __launch_bounds__(256) void winscore_kernel(const float* __restrict__ x,
                                                       const float* __restrict__ zpart,
                                                       float* __restrict__ score) {
  int b = blockIdx.x >> 6;
  int w = blockIdx.x & 63;
  int wy = w >> 3, wx = w & 7;

  __shared__ float zs[C_DIM];
  {
    float m = zpart[(size_t)(b * 8) * C_DIM + threadIdx.x];
    #pragma unroll
    for (int ch = 1; ch < 8; ++ch)
      m = fmaxf(m, zpart[(size_t)(b * 8 + ch) * C_DIM + threadIdx.x]);
    zs[threadIdx.x] = m;
  }
  __syncthreads();

  int wv = threadIdx.x >> 6;
  int ln = threadIdx.x & 63;

  float a0 = 0.f, a1 = 0.f, a2 = 0.f, a3 = 0.f;
  for (int t = 0; t < 16; ++t) {
    int tok = wv * 16 + t;
    int iy = tok >> 3, ix = tok & 7;
    int n = (wy * 8 + iy) * 64 + wx * 8 + ix;
    const float4 v = *(const float4*)(x + ((size_t)b * NS + n) * C_DIM + ln * 4);
    a0 += v.x; a1 += v.y; a2 += v.z; a3 += v.w;
  }
  const float4 z4 = ((const float4*)zs)[ln];
  float p = a0 * z4.x + a1 * z4.y + a2 * z4.z + a3 * z4.w;
  for (int off = 32; off >= 1; off >>= 1) p += __shfl_xor(p, off);

  __shared__ float wsum[4];
  if (ln == 0) wsum[wv] = p;
  __syncthreads();
  if (threadIdx.x == 0) score[blockIdx.x] = wsum[0] + wsum[1] + wsum[2] + wsum[3];
}

// ---------------- kernel 3: fused topk + gather + GEMM1 + shift + GEMM2 ----
// R10 structure -- best measured configuration of the session (81.6 us),
// reproduced at 81.8 (R16).  One block per (b,k), 256 thr / 4 waves.  TWO
// 32KB LDS buffers (xe persists; t separate).  Weights fully hoisted into
// registers, issued where latency hides under staging / barriers (lifetimes
// phase-disjoint with acc -- any additional live state across a GEMM phase
// spills; see R11/R17 postmortems).  Coalesced epilogue: up transposed
// through t_s, final phase writes whole rows (64 lanes x float4 = 1KB
// full-line stores).  2 blocks/CU (LDS-limited), 1024 grid = 2 even rounds.
// XOR swizzle: byte_in_row ^= (row & 7) << 4.
__global__ __launch_bounds__(256, 2) void fused_win(
    const float* __restrict__ x, const float* __restrict__ score,
    const unsigned short* __restrict__ Wdb, const unsigned short* __restrict__ Wub,
    const float* __restrict__ bd, const float* __restrict__ bu,
    float* __restrict__ out)
{
  __shared__ unsigned short xe_s[WTOK * C_DIM];  // 32 KB, persists whole kernel
  __shared__ unsigned short t_s[WTOK * C_DIM];   // 32 KB (t, then up)
  __shared__ float sc[NWIN];
  __shared__ int wsel_s;

  const int bk = blockIdx.x;
  const int b = bk >> 5;
  const int kk = bk & 31;
  const int tid = threadIdx.x;

  // ---- in-block top-k rank select (reproduces jax.lax.top_k order) ----
  if (tid < NWIN) sc[tid] = score[b * NWIN + tid];
  __syncthreads();
  if (tid < NWIN) {
    float v = sc[tid];
    int rank = 0;
    #pragma unroll
    for (int j = 0; j < NWIN; ++j) {
      float sj = sc[j];
      rank += (sj > v) || (sj == v && j < tid);
    }
    if (rank == kk) wsel_s = tid;
  }
  __syncthreads();
  const int wsel = wsel_s;
  const int wy = wsel >> 3, wx = wsel & 7;

  const int wv = tid >> 6;
  const int ln = tid & 63;
  const int lr = ln & 15;   // A-row / B-col / D-col
  const int lg = ln >> 4;   // k-subgroup

  const unsigned short* wdbase = Wdb + ((size_t)(wv * 64 + lr)) * C_DIM + lg * 8;
  const unsigned short* wubase = Wub + ((size_t)(wv * 64 + lr)) * C_DIM + lg * 8;

  // ---- issue GEMM1 weights first (no deps; land during staging) ----
  short8 wreg[8][4];
  #pragma unroll
  for (int ks = 0; ks < 8; ++ks)
    #pragma unroll
    for (int nt = 0; nt < 4; ++nt)
      wreg[ks][nt] = *(const short8*)(wdbase + nt * 16 * C_DIM + ks * 32);

  // ---- stage xe: all 16 loads in flight, then convert+write ----
  const int c4 = tid & 63;        // float4 column, constant per thread
  const int m0w = tid >> 6;       // starting row (0..3)
  {
    const float* xb = x + (size_t)b * NS * C_DIM + c4 * 4;
    float4 xv[16];
    #pragma unroll
    for (int i = 0; i < 16; ++i) {
      int m = m0w + i * 4;
      int n = (wy * 8 + (m >> 3)) * 64 + wx * 8 + (m & 7);
      xv[i] = *(const float4*)(xb + (size_t)n * C_DIM);
    }
    #pragma unroll
    for (int i = 0; i < 16; ++i) {
      int m = m0w + i * 4;
      ushort4 h;
      h.x = f2b(xv[i].x); h.y = f2b(xv[i].y); h.z = f2b(xv[i].z); h.w = f2b(xv[i].w);
      int byteoff = m * 512 + ((c4 * 8) ^ ((m & 7) << 4));
      *(ushort4*)((char*)xe_s + byteoff) = h;
    }
  }
  __syncthreads();

  // ---- GEMM1: t = xe @ Wd^T (weights already in regs) ----
  f32x4 acc[4][4];
  #pragma unroll
  for (int a = 0; a < 4; ++a)
    #pragma unroll
    for (int n2 = 0; n2 < 4; ++n2) acc[a][n2] = (f32x4){0.f, 0.f, 0.f, 0.f};

  #pragma unroll
  for (int ks = 0; ks < 8; ++ks) {
    const int kb = ks * 64 + lg * 16;
    short8 af[4];
    #pragma unroll
    for (int mt = 0; mt < 4; ++mt) {
      int m = mt * 16 + lr;
      af[mt] = *(const short8*)((const char*)xe_s + m * 512 + (kb ^ ((m & 7) << 4)));
    }
    #pragma unroll
    for (int mt = 0; mt < 4; ++mt)
      #pragma unroll
      for (int nt = 0; nt < 4; ++nt)
        acc[mt][nt] = __builtin_amdgcn_mfma_f32_16x16x32_bf16(af[mt], wreg[ks][nt], acc[mt][nt], 0, 0, 0);
  }

  // ---- epilogue 1: t = acc + bd -> bf16 -> t_s (swizzled); acc dies ----
  #pragma unroll
  for (int nt = 0; nt < 4; ++nt) {
    int o = wv * 64 + nt * 16 + lr;
    float bdv = bd[o];
    #pragma unroll
    for (int mt = 0; mt < 4; ++mt) {
      #pragma unroll
      for (int r = 0; r < 4; ++r) {
        int m = mt * 16 + lg * 4 + r;
        float v = acc[mt][nt][r] + bdv;
        *(unsigned short*)((char*)t_s + m * 512 + ((o * 2) ^ ((m & 7) << 4))) = f2b(v);
      }
    }
  }

  // ---- issue GEMM2 weights (land under the barrier) ----
  short8 wreg2[8][4];
  #pragma unroll
  for (int ks = 0; ks < 8; ++ks)
    #pragma unroll
    for (int nt = 0; nt < 4; ++nt)
      wreg2[ks][nt] = *(const short8*)(wubase + nt * 16 * C_DIM + ks * 32);

  __syncthreads();

  // ---- GEMM2: up = shift(t) @ Wu^T ----
  f32x4 acc2[4][4];
  #pragma unroll
  for (int a = 0; a < 4; ++a)
    #pragma unroll
    for (int n2 = 0; n2 < 4; ++n2) acc2[a][n2] = (f32x4){0.f, 0.f, 0.f, 0.f};

  #pragma unroll
  for (int ks = 0; ks < 8; ++ks) {
    const int g = ks >> 1;              // channel group (64-wide), uniform per ks
    const int dd = ((g & 1) ? -1 : 1) * ((g & 2) ? 8 : 1);
    const int kb = ks * 64 + lg * 16;
    short8 af[4];
    #pragma unroll
    for (int mt = 0; mt < 4; ++mt) {
      int m = mt * 16 + lr;
      int pos = (g & 2) ? (m >> 3) : (m & 7);
      bool ok = (g & 1) ? (pos > 0) : (pos < 7);
      int ms = m + dd;
      ms = ms < 0 ? 0 : (ms > 63 ? 63 : ms);   // safe address, result masked
      short8 v = *(const short8*)((const char*)t_s + ms * 512 + (kb ^ ((ms & 7) << 4)));
      const short8 zed = {0, 0, 0, 0, 0, 0, 0, 0};
      af[mt] = ok ? v : zed;
    }
    #pragma unroll
    for (int mt = 0; mt < 4; ++mt)
      #pragma unroll
      for (int nt = 0; nt < 4; ++nt)
        acc2[mt][nt] = __builtin_amdgcn_mfma_f32_16x16x32_bf16(af[mt], wreg2[ks][nt], acc2[mt][nt], 0, 0, 0);
  }

  __syncthreads();   // all t_s reads done; t_s is now free for up

  // ---- epilogue 2a: up (bf16) -> t_s (swizzled row-major) ----
  #pragma unroll
  for (int nt = 0; nt < 4; ++nt) {
    int c = wv * 64 + nt * 16 + lr;
    #pragma unroll
    for (int mt = 0; mt < 4; ++mt) {
      #pragma unroll
      for (int r = 0; r < 4; ++r) {
        int m = mt * 16 + lg * 4 + r;
        *(unsigned short*)((char*)t_s + m * 512 + ((c * 2) ^ ((m & 7) << 4))) = f2b(acc2[mt][nt][r]);
      }
    }
  }
  __syncthreads();

  // ---- epilogue 2b: coalesced row writes: out = xe + up + bu ----
  // wave = fixed m0w; 64 lanes cover the row -> 1KB contiguous float4 stores.
  {
    const float4 bu4 = *(const float4*)(bu + c4 * 4);
    float* ob = out + (size_t)bk * WTOK * C_DIM + c4 * 4;
    #pragma unroll
    for (int i = 0; i < 16; ++i) {
      int m = m0w + i * 4;
      int off = m * 512 + ((c4 * 8) ^ ((m & 7) << 4));
      ushort4 xe4 = *(const ushort4*)((const char*)xe_s + off);
      ushort4 up4 = *(const ushort4*)((const char*)t_s + off);
      float4 o;
      o.x = b2f(xe4.x) + b2f(up4.x) + bu4.x;
      o.y = b2f(xe4.y) + b2f(up4.y) + bu4.y;
      o.z = b2f(xe4.z) + b2f(up4.z) + bu4.z;
      o.w = b2f(xe4.w) + b2f(up4.w) + bu4.w;
      *(float4*)(ob + (size_t)m * C_DIM) = o;
    }
  }
}

// ---------------- launch ----------------
extern "C" void kernel_launch(void* const* d_in, const int* in_sizes, int n_in,
                              void* d_out, int out_size, void* d_ws, size_t ws_size,
                              hipStream_t stream) {
  const float* z  = (const float*)d_in[0];
  const float* x  = (const float*)d_in[1];
  const float* Wd = (const float*)d_in[2];
  const float* bd = (const float*)d_in[3];
  const float* Wu = (const float*)d_in[4];
  const float* bu = (const float*)d_in[5];
  float* out = (float*)d_out;

  char* ws = (char*)d_ws;
  unsigned short* Wdb = (unsigned short*)(ws);            // 0      .. 131072
  unsigned short* Wub = (unsigned short*)(ws + 131072);   // 131072 .. 262144
  float* zpart = (float*)(ws + 262144);                   // 262144 .. 524288 (32*8*256 f32)
  float* score = (float*)(ws + 524288);                   // 524288 .. 532480

  hipLaunchKernelGGL(prep_kernel, dim3(320), dim3(256), 0, stream, Wd, Wu, Wdb, Wub, z, zpart);
  hipLaunchKernelGGL(winscore_kernel, dim3(B_SZ * NWIN), dim3(256), 0, stream, x, zpart, score);
  hipLaunchKernelGGL(fused_win, dim3(B_SZ * TOPK_K), dim3(256), 0, stream,
                     x, score, Wdb, Wub, bd, bu, out);
}